// Round 17
// baseline (176.165 us; speedup 1.0000x reference)
//
#include <hip/hip_runtime.h>

typedef __attribute__((ext_vector_type(8))) short bf16x8;
typedef __attribute__((ext_vector_type(8))) unsigned short u16x8;
typedef __attribute__((ext_vector_type(4))) float f32x4;

// ---------------- ws layout (bytes) ----------------
#define WSB_FEAT 0u
#define WSB_FQ   393216u
#define WSB_FK   786432u
#define WSB_FV   1179648u
#define WSB_META 1572864u
#define WSB_HA0  1574912u
#define WSB_HA1  18352128u
#define WSB_W1H  35129344u
#define WSB_ZERO 37193728u     // 64 floats in the free ex-W1l gap
#define WSB_W234 39258112u
#define WSB_FEAT1 39651328u

#define NH 256

__device__ __forceinline__ float gelu_f(float x) {
  return 0.5f * x * (1.0f + erff(x * 0.70710678118654752f));
}
__device__ __forceinline__ unsigned short f2bf(float x) {
  unsigned int u = __float_as_uint(x);
  u += 0x7fffu + ((u >> 16) & 1u);
  return (unsigned short)(u >> 16);
}
__device__ __forceinline__ float bf2f(unsigned short h) {
  return __uint_as_float(((unsigned int)h) << 16);
}
__device__ __forceinline__ void split2(float a, unsigned short& hi, unsigned short& lo) {
  hi = f2bf(a);
  lo = f2bf(a - bf2f(hi));
}
// packed RNE f32->bf16 pair: low16 = cvt(a), high16 = cvt(b)
__device__ __forceinline__ unsigned int cvt_pk_bf16(float a, float b) {
  unsigned int r;
  asm("v_cvt_pk_bf16_f32 %0, %1, %2" : "=v"(r) : "v"(a), "v"(b));
  return r;
}
// async global->LDS, 4B per lane; LDS dest = wave-uniform base + lane*4
__device__ __forceinline__ void gload_lds4(const float* g, float* l) {
  __builtin_amdgcn_global_load_lds((const __attribute__((address_space(1))) void*)g,
                                   (__attribute__((address_space(3))) void*)l, 4, 0, 0);
}

// ---------------- pre: conv1 halves (0..383) + setup (384) + repack (385..534) ----------------
__global__ __launch_bounds__(512) void pre_kernel(
    const float* __restrict__ in, const float* __restrict__ W,
    const float* __restrict__ times, const float* __restrict__ Bpe,
    const float* __restrict__ Wpb, const float* __restrict__ bpb,
    const float* __restrict__ W1, const float* __restrict__ W2,
    const float* __restrict__ W3, const float* __restrict__ W4,
    float* __restrict__ feat0, float* __restrict__ feat1,
    float* __restrict__ meta, float* __restrict__ zbuf,
    unsigned short* __restrict__ W1h, unsigned short* __restrict__ W234h) {
  __shared__ float win[4896];
  const int tid = threadIdx.x;
  if (blockIdx.x < 384) {
    const int half = blockIdx.x / 192;
    const int sp = blockIdx.x - half*192;
    const int t = sp >> 5, y = sp & 31;
    const int x = tid & 31, cop = tid >> 5;   // 0..15
    float acc = 0.f;
    const int cbase = half*32;
    for (int ci0 = cbase; ci0 < cbase + 32; ci0 += 16) {
      __syncthreads();
      for (int e = tid; e < 4896; e += 512) {
        int ci = e / 306, rem = e - ci*306;
        int tz = rem / 102, rem2 = rem - tz*102;
        int dy = rem2 / 34, xx = rem2 - dy*34;
        int gt = t + tz - 1, gy = y + dy - 1, gx = xx - 1;
        float v = 0.f;
        if (gt >= 0 && gt < 6 && gy >= 0 && gy < 32 && gx >= 0 && gx < 32)
          v = in[((ci0 + ci)*6 + gt)*1024 + gy*32 + gx];
        win[e] = v;
      }
      __syncthreads();
      for (int ci = 0; ci < 16; ++ci) {
        const float* w0 = W + (cop*64 + ci0 + ci)*27;
        const float* wr = win + ci*306;
        #pragma unroll
        for (int tz = 0; tz < 3; ++tz)
          #pragma unroll
          for (int dy = 0; dy < 3; ++dy)
            #pragma unroll
            for (int dx = 0; dx < 3; ++dx)
              acc += wr[(tz*3 + dy)*34 + x + dx] * w0[(tz*3 + dy)*3 + dx];
      }
    }
    float* dst = half ? feat1 : feat0;
    dst[(t*1024 + y*32 + x)*16 + cop] = acc;
  } else if (blockIdx.x == 384) {
    if (tid >= 64 && tid < 128) zbuf[tid - 64] = 0.f;   // zero page for OOB async loads
    const float t5f = times[0] * 5.0f;
    const double ct_d = rint((double)t5f);
    const int ct = (int)ct_d;
    const double rt = ((double)t5f - ct_d) * 2.0 / 5.0;
    const float rtf = (float)rt;
    if (tid == 0) {
      float iz = ((rtf + 1.0f)*5.0f - 1.0f) / 2.0f;
      float z0 = floorf(iz);
      meta[0] = iz - z0;
      meta[1] = z0;
      for (int d = 0; d < 5; ++d) {
        int ix = ct + d - 2; ix = ix < 0 ? 0 : (ix > 5 ? 5 : ix);
        meta[2 + d] = (float)ix;
      }
    }
    if (tid < 40) {
      int dt = tid >> 3, h = tid & 7;
      double tcd = rt - (double)(dt - 2) * 2.0 / 5.0;
      float rs = (float)tcd * 5.0f;
      float acc = bpb[h];
      for (int j = 0; j < 10; ++j) {
        float pr = rs * Bpe[j*3 + 0];
        acc += sinf(pr) * Wpb[j*8 + h] + cosf(pr) * Wpb[(30+j)*8 + h];
      }
      meta[16 + tid] = acc;
    }
    if (tid < 224) {
      int p = tid / 56, ky = (tid >> 3) % 7, h = tid & 7;
      float r = (float)(2*p - 3) * 0.25f - 2.0f * (float)(ky - 3);
      float accy = 0.f, accx = 0.f;
      for (int j = 0; j < 10; ++j) {
        float pry = r * Bpe[(10+j)*3 + 1];
        accy += sinf(pry) * Wpb[(10+j)*8 + h] + cosf(pry) * Wpb[(40+j)*8 + h];
        float prx = r * Bpe[(20+j)*3 + 2];
        accx += sinf(prx) * Wpb[(20+j)*8 + h] + cosf(prx) * Wpb[(50+j)*8 + h];
      }
      meta[64 + tid]  = accy;
      meta[288 + tid] = accx;
    }
  } else if (tid < 256) {
    const int rblk = blockIdx.x - 385;
    const int n = tid;
    unsigned short tmp[32];
    if (rblk < 126) {
      const int s = rblk;
      #pragma unroll
      for (int j = 0; j < 32; ++j) {
        int p = s*32 + j;
        float w = 0.f;
        if (p < 4000) {
          int dt = p / 800, r = p - dt*800;
          if (r < 784) w = W1[(dt*784 + r)*256 + n];
        } else {
          int j2 = p - 4000;
          if (j2 < 18) w = W1[(3920 + j2)*256 + n];
        }
        tmp[j] = f2bf(w);
      }
      unsigned short* dh = W1h + ((size_t)(s*256 + n))*32;
      #pragma unroll
      for (int v = 0; v < 4; ++v) {
        u16x8 xv;
        #pragma unroll
        for (int j = 0; j < 8; ++j) xv[j] = tmp[v*8 + j];
        *(u16x8*)(dh + v*8) = xv;
      }
    } else {
      const int blk = rblk - 126;
      const int m = blk >> 3, s = blk & 7;
      const float* Wm = (m == 0) ? W2 : ((m == 1) ? W3 : W4);
      #pragma unroll
      for (int j = 0; j < 32; ++j) tmp[j] = f2bf(Wm[(s*32 + j)*256 + n]);
      unsigned short* dh = W234h + (size_t)m*65536 + ((size_t)(s*256 + n))*32;
      #pragma unroll
      for (int v = 0; v < 4; ++v) {
        u16x8 xv;
        #pragma unroll
        for (int j = 0; j < 8; ++j) xv[j] = tmp[v*8 + j];
        *(u16x8*)(dh + v*8) = xv;
      }
    }
  }
}

// ---------------- fused conv q/k/v; grid 576 = 3 mats x 192 (t,y); combines feat partials ----------------
__global__ __launch_bounds__(512) void conv_qkv_kernel(
    const float* __restrict__ f0, const float* __restrict__ f1,
    const float* __restrict__ bch,
    const float* __restrict__ Wq, const float* __restrict__ bq,
    const float* __restrict__ Wk, const float* __restrict__ bk,
    const float* __restrict__ Wv, const float* __restrict__ bv,
    float* __restrict__ fq, float* __restrict__ fk, float* __restrict__ fv) {
  __shared__ float win[4896];
  __shared__ float sbch[16];
  const int blk = blockIdx.x;
  const int m = blk / 192;
  const int sp = blk - m*192;
  const int t = sp >> 5, y = sp & 31;
  const int tid = threadIdx.x;
  const int x = tid & 31, cop = tid >> 5;
  if (tid < 16) sbch[tid] = bch[tid];
  __syncthreads();
  for (int e = tid; e < 4896; e += 512) {
    int tz = e / 1632, rem = e - tz*1632;
    int dy = rem / 544, rem2 = rem - dy*544;
    int ci = rem2 / 34, xx = rem2 - ci*34;
    int gt = t + tz - 1, gy = y + dy - 1, gx = xx - 1;
    float v = 0.f;
    if (gt >= 0 && gt < 6 && gy >= 0 && gy < 32 && gx >= 0 && gx < 32) {
      const int idx = ((gt*32 + gy)*32 + gx)*16 + ci;
      v = f0[idx] + f1[idx] + sbch[ci];
    }
    win[e] = v;
  }
  __syncthreads();
  const float* Wm = (m == 0) ? Wq : ((m == 1) ? Wk : Wv);
  const float* bm = (m == 0) ? bq : ((m == 1) ? bk : bv);
  float*       fm = (m == 0) ? fq : ((m == 1) ? fk : fv);
  float a0 = 0.f, a1 = 0.f;
  for (int ci = 0; ci < 16; ci += 2) {
    const float* w0 = Wm + (cop*16 + ci)*27;
    #pragma unroll
    for (int tz = 0; tz < 3; ++tz)
      #pragma unroll
      for (int dy = 0; dy < 3; ++dy) {
        const float* wr0 = win + ((tz*3 + dy)*16 + ci)*34 + x;
        #pragma unroll
        for (int dx = 0; dx < 3; ++dx) {
          const int tap = (tz*3 + dy)*3 + dx;
          a0 += wr0[dx]      * w0[tap];
          a1 += wr0[34 + dx] * w0[27 + tap];
        }
      }
  }
  fm[(t*1024 + y*32 + x)*16 + cop] = a0 + a1 + bm[cop];
}

// ---------------- attn: async K/V issue into (sKn, sVn) ----------------
__device__ __forceinline__ void issue_kv_async(
    int tg, int cj0, int ci0, int tid,
    const float* __restrict__ fk, const float* __restrict__ fv,
    const float* __restrict__ zbuf, float* sKn, float* sVn) {
  #pragma unroll
  for (int u = 0; u < 4; ++u) {
    const int e = tid + u*512;
    const int sel = e >> 10, r = e & 1023;     // sel, base uniform per wave
    const int wy8 = r >> 7, wx8 = (r >> 4) & 7, c = r & 15;
    const int gy = cj0 + wy8 - 3, gx = ci0 + wx8 - 3;
    const bool ok = (gy >= 0 && gy < 32 && gx >= 0 && gx < 32);
    const float* src = ok ? ((sel ? fv : fk) + (((tg*32 + gy)*32 + gx)*16 + c))
                          : (zbuf + c);
    float* dstbase = (sel ? sVn : sKn) + (r & ~63);
    gload_lds4(src, dstbase);
  }
}

// ---------------- attn dt-phase body; K/V already resident in (sKc,sVc) ----------------
// Entry contract: preceded by a __syncthreads() that also drained the async loads.
template<int CHL, int CHH, bool PRE>
__device__ __forceinline__ void attn_dt(
    int dt, int tg_next, int cj0, int ci0, int tid,
    int q, int h, int ay, int ax, int py, int px,
    int goct, int qr, int nb0,
    const float* __restrict__ fk, const float* __restrict__ fv,
    const float* __restrict__ zbuf,
    const unsigned short* __restrict__ W1h,
    const float* sPt, const float* sPy, const float* sPx,
    const float* sQh,
    const float* sKc, const float* sVc, float* sKn, float* sVn,
    unsigned short* sA0, unsigned short* sA1,
    f32x4 (&acc)[4][2]) {
  // pass 1: exps into registers + denom (no max-subtraction; |score| small)
  const float qv0 = sQh[q*16 + 2*h], qv1 = sQh[q*16 + 2*h + 1];
  const float ptv = sPt[dt*8 + h];
  float ev[49];
  float ssum = 0.f;
  #pragma unroll
  for (int ky = 0; ky < 7; ++ky) {
    const float basey = ptv + sPy[(py*7 + ky)*8 + h];
    #pragma unroll
    for (int kx = 0; kx < 7; ++kx) {
      const float2 kv = *(const float2*)&sKc[((ay + ky)*8 + ax + kx)*16 + 2*h];
      const float sc = (qv0*kv.x + qv1*kv.y) * 0.70710678118654752f + basey + sPx[(px*7 + kx)*8 + h];
      const float x = __expf(sc);
      ev[ky*7 + kx] = x;
      ssum += x;
    }
  }
  const float dinv = 1.f / ssum;

  // issue async K/V for next dt; completes at the next barrier's vmcnt drain
  if (PRE) issue_kv_async(tg_next, cj0, ci0, tid, fk, fv, zbuf, sKn, sVn);

#define FILL_CHUNK(CH, BUF) do {                                            \
    _Pragma("unroll")                                                       \
    for (int kk = 0; kk < 10; ++kk) {                                       \
      const int k = (CH)*10 + kk;                                           \
      float a0 = 0.f, a1 = 0.f;                                             \
      if (k < 49) {                                                         \
        const int ky = k / 7, kx = k - ky*7;                                \
        const float e2 = ev[k] * dinv;                                      \
        const float2 vv = *(const float2*)&sVc[((ay + ky)*8 + ax + kx)*16 + 2*h]; \
        a0 = e2 * vv.x; a1 = e2 * vv.y;                                     \
      }                                                                     \
      const int off = ((((kk >> 1)*4 + (kk & 1)*2 + (h >> 2))*4 + (q >> 4))*16 + (q & 15))*8 + 2*(h & 3); \
      *(unsigned int*)&(BUF)[off] = cvt_pk_bf16(a0, a1);                    \
    } } while (0)

  FILL_CHUNK(CHL, sA0);
  __syncthreads();
  #pragma unroll
  for (int ch = CHL; ch <= CHH; ++ch) {
    unsigned short* bufR = ((ch - CHL) & 1) ? sA1 : sA0;
    unsigned short* bufW = ((ch - CHL) & 1) ? sA0 : sA1;
    #pragma unroll
    for (int sc2 = 0; sc2 < 5; ++sc2) {
      const int s_g = dt*25 + ch*5 + sc2;
      const unsigned short* bh_p = W1h + (size_t)(s_g*256 + nb0 + qr)*32 + goct*8;
      const bf16x8 bh0 = *(const bf16x8*)bh_p;
      const bf16x8 bh1 = *(const bf16x8*)(bh_p + 512);
      #pragma unroll
      for (int mt = 0; mt < 4; ++mt) {
        const int aoff = (((sc2*4 + goct)*4 + mt)*16 + qr)*8;
        const bf16x8 ah = *(const bf16x8*)&bufR[aoff];
        acc[mt][0] = __builtin_amdgcn_mfma_f32_16x16x32_bf16(ah, bh0, acc[mt][0], 0, 0, 0);
        acc[mt][1] = __builtin_amdgcn_mfma_f32_16x16x32_bf16(ah, bh1, acc[mt][1], 0, 0, 0);
      }
    }
    if (ch < CHH) FILL_CHUNK(ch + 1, bufW);
    __syncthreads();
  }
#undef FILL_CHUNK
}

// ---------------- fused attention + MLP layer 1 (MFMA, A=bf16, W1=bf16) ----------------
// grid 512: block = 2x2 cells (64 q) x K-half (dt-split). 512 threads = 8 waves.
// K/V double-buffered in LDS; staged via async global_load_lds (no VGPR round-trip).
__global__ __launch_bounds__(512, 4) void attn_l1_kernel(
    const float* __restrict__ fq, const float* __restrict__ fk,
    const float* __restrict__ fv, const float* __restrict__ meta,
    const float* __restrict__ zbuf,
    const unsigned short* __restrict__ W1h,
    float* __restrict__ hA0, float* __restrict__ hA1) {
  __shared__ float sPt[40], sPy[224], sPx[224], sMeta[8];
  __shared__ float sQh[1024];
  __shared__ float sK0[1024], sV0[1024];
  __shared__ float sK1[1024], sV1[1024];
  __shared__ __align__(16) unsigned short sA0[10240];  // [5 sl][4 g][4 mt][16 q][8]
  __shared__ __align__(16) unsigned short sA1[10240];

  const int tid = threadIdx.x;
  const int cp = blockIdx.x >> 1, bh = blockIdx.x & 1;
  const int cj0 = (cp >> 4) * 2, ci0 = (cp & 15) * 2;

  if (tid < 8) sMeta[tid] = meta[tid];
  if (tid < 40) sPt[tid] = meta[16 + tid];
  if (tid < 224) { sPy[tid] = meta[64 + tid]; sPx[tid] = meta[288 + tid]; }
  __syncthreads();
  const float wz = sMeta[0];
  const int z0 = (int)sMeta[1];
  const int tgz0 = (int)sMeta[2 + z0];
  const int tgz1 = (int)sMeta[3 + z0];
  const int tgd[5] = {(int)sMeta[2], (int)sMeta[3], (int)sMeta[4], (int)sMeta[5], (int)sMeta[6]};

  // issue first dt's K/V async; its latency hides under the trilinear sampling
  issue_kv_async(bh ? tgd[2] : tgd[0], cj0, ci0, tid, fk, fv, zbuf, sK0, sV0);

  // trilinear sample of feat_q -> sQh[q][c], q in 0..63 (8x8 pixel patch)
  for (int e = tid; e < 1024; e += 512) {
    const int q = e >> 4, c = e & 15;
    const int pyp = q >> 3, pxp = q & 7;
    const int cj = cj0 + (pyp >> 2), ci = ci0 + (pxp >> 2);
    const int py = pyp & 3, px = pxp & 3;
    const int y0 = cj + ((py < 2) ? -1 : 0);
    const int x0 = ci + ((px < 2) ? -1 : 0);
    const float wy = (py == 0) ? 0.625f : (py == 1) ? 0.875f : (py == 2) ? 0.125f : 0.375f;
    const float wx = (px == 0) ? 0.625f : (px == 1) ? 0.875f : (px == 2) ? 0.125f : 0.375f;
    float s = 0.f;
    #pragma unroll
    for (int dz = 0; dz < 2; ++dz) {
      const int tg = dz ? tgz1 : tgz0;
      const float wzz = dz ? wz : (1.f - wz);
      #pragma unroll
      for (int dy = 0; dy < 2; ++dy) {
        const int yy = y0 + dy;
        const float wyy = dy ? wy : (1.f - wy);
        if (yy < 0 || yy > 31) continue;
        #pragma unroll
        for (int dx = 0; dx < 2; ++dx) {
          const int xx = x0 + dx;
          const float wxx = dx ? wx : (1.f - wx);
          if (xx < 0 || xx > 31) continue;
          s += ((wzz * wyy) * wxx) * fq[((tg*32 + yy)*32 + xx)*16 + c];
        }
      }
    }
    sQh[e] = s;
  }
  __syncthreads();   // sQh visible + async K/V drained

  f32x4 acc[4][2];
  #pragma unroll
  for (int a = 0; a < 4; ++a) {
    acc[a][0] = (f32x4){0.f, 0.f, 0.f, 0.f};
    acc[a][1] = (f32x4){0.f, 0.f, 0.f, 0.f};
  }

  const int lane = tid & 63, wid = tid >> 6;
  const int goct = lane >> 4, qr = lane & 15;
  const int nb0 = wid * 32;
  const int q = tid >> 3, h = tid & 7;
  const int ay = q >> 5, ax = (q >> 2) & 1;
  const int py = (q >> 3) & 3, px = q & 3;

  if (!bh) {
    attn_dt<0,4,true >(0, tgd[1], cj0, ci0, tid, q, h, ay, ax, py, px, goct, qr, nb0,
                       fk, fv, zbuf, W1h, sPt, sPy, sPx, sQh, sK0, sV0, sK1, sV1, sA0, sA1, acc);
    attn_dt<0,4,true >(1, tgd[2], cj0, ci0, tid, q, h, ay, ax, py, px, goct, qr, nb0,
                       fk, fv, zbuf, W1h, sPt, sPy, sPx, sQh, sK1, sV1, sK0, sV0, sA0, sA1, acc);
    attn_dt<0,1,false>(2, 0,      cj0, ci0, tid, q, h, ay, ax, py, px, goct, qr, nb0,
                       fk, fv, zbuf, W1h, sPt, sPy, sPx, sQh, sK0, sV0, sK1, sV1, sA0, sA1, acc);
    // tail k-step: 16 rows of sq + 2 rows of 0.5 + 14 zero rows
    for (int e = tid; e < 2048; e += 512) {
      const int q2 = e >> 5, r2 = e & 31;
      const float a = (r2 < 16) ? sQh[q2*16 + r2] : ((r2 < 18) ? 0.5f : 0.f);
      const int off = ((((r2 >> 3))*4 + (q2 >> 4))*16 + (q2 & 15))*8 + (r2 & 7);
      sA0[off] = f2bf(a);
    }
    __syncthreads();
    const unsigned short* bh_p = W1h + (size_t)(125*256 + nb0 + qr)*32 + goct*8;
    const bf16x8 bh0 = *(const bf16x8*)bh_p;
    const bf16x8 bh1 = *(const bf16x8*)(bh_p + 512);
    #pragma unroll
    for (int mt = 0; mt < 4; ++mt) {
      const int aoff = ((goct*4 + mt)*16 + qr)*8;
      const bf16x8 ah = *(const bf16x8*)&sA0[aoff];
      acc[mt][0] = __builtin_amdgcn_mfma_f32_16x16x32_bf16(ah, bh0, acc[mt][0], 0, 0, 0);
      acc[mt][1] = __builtin_amdgcn_mfma_f32_16x16x32_bf16(ah, bh1, acc[mt][1], 0, 0, 0);
    }
  } else {
    attn_dt<2,4,true >(2, tgd[3], cj0, ci0, tid, q, h, ay, ax, py, px, goct, qr, nb0,
                       fk, fv, zbuf, W1h, sPt, sPy, sPx, sQh, sK0, sV0, sK1, sV1, sA0, sA1, acc);
    attn_dt<0,4,true >(3, tgd[4], cj0, ci0, tid, q, h, ay, ax, py, px, goct, qr, nb0,
                       fk, fv, zbuf, W1h, sPt, sPy, sPx, sQh, sK1, sV1, sK0, sV0, sA0, sA1, acc);
    attn_dt<0,4,false>(4, 0,      cj0, ci0, tid, q, h, ay, ax, py, px, goct, qr, nb0,
                       fk, fv, zbuf, W1h, sPt, sPy, sPx, sQh, sK0, sV0, sK1, sV1, sA0, sA1, acc);
  }

  // epilogue: raw partial store
  float* hp = bh ? hA1 : hA0;
  #pragma unroll
  for (int nt = 0; nt < 2; ++nt) {
    const int n = nb0 + nt*16 + qr;
    #pragma unroll
    for (int mt = 0; mt < 4; ++mt) {
      #pragma unroll
      for (int r = 0; r < 4; ++r) {
        const int ql = mt*16 + goct*4 + r;
        const int row = (cj0*4 + (ql >> 3))*128 + ci0*4 + (ql & 7);
        hp[row*NH + n] = acc[mt][nt][r];
      }
    }
  }
}

// ---------------- fused MLP l2+l3+l4+out: block = 32 rows, grid 512 ----------------
__global__ __launch_bounds__(512) void mlp234o_kernel(
    const float* __restrict__ hA0, const float* __restrict__ hA1,
    const unsigned short* __restrict__ W234h, const float* __restrict__ b1,
    const float* __restrict__ b2, const float* __restrict__ b3,
    const float* __restrict__ b4, const float* __restrict__ W5,
    const float* __restrict__ b5, float* __restrict__ out) {
  __shared__ __align__(16) unsigned short aH[8192];  // [s8][g4][mt2][q16][e8]
  __shared__ __align__(16) unsigned short aL[8192];
  __shared__ float sW5[768];
  __shared__ float sB5[3];

  const int tid = threadIdx.x, lane = tid & 63, wid = tid >> 6;
  const int goct = lane >> 4, qr = lane & 15, nb0 = wid * 32;
  const int qbase = blockIdx.x * 32;

  for (int e = tid; e < 768; e += 512) sW5[e] = W5[e];
  if (tid < 3) sB5[tid] = b5[tid];

  // combine partials -> h1 = gelu(p0+p1+b1) -> a-frag layout (hi/lo)
  {
    #pragma unroll
    for (int u = 0; u < 2; ++u) {
      const int idx = tid*2 + u;
      const int q0_ = idx >> 5, rem = idx & 31;
      const int s0_ = rem >> 2, g = rem & 3;
      const size_t off = (size_t)(qbase + q0_)*NH + s0_*32 + g*8;
      const float4 pa0 = *(const float4*)(hA0 + off);
      const float4 pa1 = *(const float4*)(hA0 + off + 4);
      const float4 pb0 = *(const float4*)(hA1 + off);
      const float4 pb1 = *(const float4*)(hA1 + off + 4);
      const float4 bb0 = *(const float4*)(b1 + s0_*32 + g*8);
      const float4 bb1 = *(const float4*)(b1 + s0_*32 + g*8 + 4);
      float vals[8] = {pa0.x + pb0.x + bb0.x, pa0.y + pb0.y + bb0.y,
                       pa0.z + pb0.z + bb0.z, pa0.w + pb0.w + bb0.w,
                       pa1.x + pb1.x + bb1.x, pa1.y + pb1.y + bb1.y,
                       pa1.z + pb1.z + bb1.z, pa1.w + pb1.w + bb1.w};
      bf16x8 hiv, lov;
      #pragma unroll
      for (int j = 0; j < 8; ++j) {
        const float v = gelu_f(vals[j]);
        unsigned short h_, l_;
        split2(v, h_, l_);
        hiv[j] = (short)h_; lov[j] = (short)l_;
      }
      const int ao = (((s0_*4 + g)*2 + (q0_ >> 4))*16 + (q0_ & 15))*8;
      *(bf16x8*)&aH[ao] = hiv;
      *(bf16x8*)&aL[ao] = lov;
    }
  }

  for (int layer = 0; layer < 3; ++layer) {
    const unsigned short* Wh = W234h + (size_t)layer*65536;
    const float* bptr = (layer == 0) ? b2 : ((layer == 1) ? b3 : b4);
    __syncthreads();
    f32x4 acc[2][2];
    #pragma unroll
    for (int a = 0; a < 2; ++a) {
      acc[a][0] = (f32x4){0.f, 0.f, 0.f, 0.f};
      acc[a][1] = (f32x4){0.f, 0.f, 0.f, 0.f};
    }
    #pragma unroll
    for (int s = 0; s < 8; ++s) {
      const unsigned short* bh_p = Wh + (size_t)(s*256 + nb0 + qr)*32 + goct*8;
      const bf16x8 bh0 = *(const bf16x8*)bh_p;
      const bf16x8 bh1 = *(const bf16x8*)(bh_p + 512);
      #pragma unroll
      for (int mt = 0; mt < 2; ++mt) {
        const int aoff = (((s*4 + goct)*2 + mt)*16 + qr)*8;
        const bf16x8 ah = *(const bf16x8*)&aH[aoff];
        const bf16x8 al = *(const bf16x8*)&aL[aoff];
        acc[mt][0] = __builtin_amdgcn_mfma_f32_16x16x32_bf16(ah, bh0, acc[mt][0], 0, 0, 0);
        acc[mt][0] = __builtin_amdgcn_mfma_f32_16x16x32_bf16(al, bh0, acc[mt][0], 0, 0, 0);
        acc[mt][1] = __builtin_amdgcn_mfma_f32_16x16x32_bf16(ah, bh1, acc[mt][1], 0, 0, 0);
        acc[mt][1] = __builtin_amdgcn_mfma_f32_16x16x32_bf16(al, bh1, acc[mt][1], 0, 0, 0);
      }
    }
    __syncthreads();
    #pragma unroll
    for (int nt = 0; nt < 2; ++nt) {
      const int n = nb0 + nt*16 + qr;
      const float bb = bptr[n];
      #pragma unroll
      for (int mt = 0; mt < 2; ++mt) {
        #pragma unroll
        for (int r = 0; r < 4; ++r) {
          const int qq = mt*16 + goct*4 + r;
          const float v = gelu_f(acc[mt][nt][r] + bb);
          unsigned short h_, l_; split2(v, h_, l_);
          const int ao = ((((n >> 5)*4 + ((n >> 3) & 3))*2 + mt)*16 + (qq & 15))*8 + (n & 7);
          aH[ao] = h_; aL[ao] = l_;
        }
      }
    }
  }
  __syncthreads();
  if (tid < 96) {
    const int c = tid >> 5, qq = tid & 31;
    const int mt = qq >> 4, qrr = qq & 15;
    float a = sB5[c];
    #pragma unroll 4
    for (int k8 = 0; k8 < 32; ++k8) {
      const int ao = ((k8*2 + mt)*16 + qrr)*8;
      const bf16x8 hv = *(const bf16x8*)&aH[ao];
      const bf16x8 lv = *(const bf16x8*)&aL[ao];
      #pragma unroll
      for (int j = 0; j < 8; ++j)
        a += (bf2f((unsigned short)hv[j]) + bf2f((unsigned short)lv[j])) * sW5[(k8*8 + j)*3 + c];
    }
    out[c*16384 + qbase + qq] = a;
  }
}

// ---------------- launch ----------------
extern "C" void kernel_launch(void* const* d_in, const int* in_sizes, int n_in,
                              void* d_out, int out_size, void* d_ws, size_t ws_size,
                              hipStream_t stream) {
  const float* feat_img = (const float*)d_in[0];
  const float* times    = (const float*)d_in[2];
  const float* W_ch     = (const float*)d_in[3];
  const float* b_ch     = (const float*)d_in[4];
  const float* W_q      = (const float*)d_in[5];
  const float* b_q      = (const float*)d_in[6];
  const float* W_k      = (const float*)d_in[7];
  const float* b_k      = (const float*)d_in[8];
  const float* W_v      = (const float*)d_in[9];
  const float* b_v      = (const float*)d_in[10];
  const float* B_pe     = (const float*)d_in[11];
  const float* W_pb     = (const float*)d_in[12];
  const float* b_pb     = (const float*)d_in[13];
  const float* W1       = (const float*)d_in[14];
  const float* b1       = (const float*)d_in[15];
  const float* W2       = (const float*)d_in[16];
  const float* b2       = (const float*)d_in[17];
  const float* W3       = (const float*)d_in[18];
  const float* b3       = (const float*)d_in[19];
  const float* W4       = (const float*)d_in[20];
  const float* b4       = (const float*)d_in[21];
  const float* W5       = (const float*)d_in[22];
  const float* b5       = (const float*)d_in[23];

  char* wsb = (char*)d_ws;
  float* feat0 = (float*)(wsb + WSB_FEAT);
  float* feat1 = (float*)(wsb + WSB_FEAT1);
  float* fq   = (float*)(wsb + WSB_FQ);
  float* fk   = (float*)(wsb + WSB_FK);
  float* fv   = (float*)(wsb + WSB_FV);
  float* meta = (float*)(wsb + WSB_META);
  float* zbuf = (float*)(wsb + WSB_ZERO);
  float* hA0  = (float*)(wsb + WSB_HA0);
  float* hA1  = (float*)(wsb + WSB_HA1);
  unsigned short* W1h   = (unsigned short*)(wsb + WSB_W1H);
  unsigned short* W234h = (unsigned short*)(wsb + WSB_W234);

  pre_kernel<<<535, 512, 0, stream>>>(feat_img, W_ch, times, B_pe, W_pb, b_pb,
                                      W1, W2, W3, W4, feat0, feat1, meta, zbuf, W1h, W234h);
  conv_qkv_kernel<<<576, 512, 0, stream>>>(feat0, feat1, b_ch,
                                           W_q, b_q, W_k, b_k, W_v, b_v, fq, fk, fv);
  attn_l1_kernel<<<512, 512, 0, stream>>>(fq, fk, fv, meta, zbuf, W1h, hA0, hA1);
  mlp234o_kernel<<<512, 512, 0, stream>>>(hA0, hA1, W234h, b1, b2, b3, b4, W5, b5, (float*)d_out);
}

// Round 18
// 152.582 us; speedup vs baseline: 1.1546x; 1.1546x over previous
//
#include <hip/hip_runtime.h>

typedef __attribute__((ext_vector_type(8))) short bf16x8;
typedef __attribute__((ext_vector_type(8))) unsigned short u16x8;
typedef __attribute__((ext_vector_type(4))) float f32x4;

// ---------------- ws layout (bytes) ----------------
#define WSB_FEAT 0u
#define WSB_FQ   393216u
#define WSB_FK   786432u
#define WSB_FV   1179648u
#define WSB_META 1572864u
#define WSB_HA0  1574912u
#define WSB_HA1  18352128u
#define WSB_W1H  35129344u
#define WSB_W234 39258112u
#define WSB_FEAT1 39651328u

#define NH 256

__device__ __forceinline__ float gelu_f(float x) {
  return 0.5f * x * (1.0f + erff(x * 0.70710678118654752f));
}
__device__ __forceinline__ unsigned short f2bf(float x) {
  unsigned int u = __float_as_uint(x);
  u += 0x7fffu + ((u >> 16) & 1u);
  return (unsigned short)(u >> 16);
}
__device__ __forceinline__ float bf2f(unsigned short h) {
  return __uint_as_float(((unsigned int)h) << 16);
}
__device__ __forceinline__ void split2(float a, unsigned short& hi, unsigned short& lo) {
  hi = f2bf(a);
  lo = f2bf(a - bf2f(hi));
}
// packed RNE f32->bf16 pair: low16 = cvt(a), high16 = cvt(b); 1 instr replaces ~10
__device__ __forceinline__ unsigned int cvt_pk_bf16(float a, float b) {
  unsigned int r;
  asm("v_cvt_pk_bf16_f32 %0, %1, %2" : "=v"(r) : "v"(a), "v"(b));
  return r;
}

// ---------------- pre: conv1 halves (0..383) + setup (384) + repack (385..534) ----------------
__global__ __launch_bounds__(512) void pre_kernel(
    const float* __restrict__ in, const float* __restrict__ W,
    const float* __restrict__ times, const float* __restrict__ Bpe,
    const float* __restrict__ Wpb, const float* __restrict__ bpb,
    const float* __restrict__ W1, const float* __restrict__ W2,
    const float* __restrict__ W3, const float* __restrict__ W4,
    float* __restrict__ feat0, float* __restrict__ feat1,
    float* __restrict__ meta,
    unsigned short* __restrict__ W1h, unsigned short* __restrict__ W234h) {
  __shared__ float win[4896];
  const int tid = threadIdx.x;
  if (blockIdx.x < 384) {
    // conv1 partial: half = which 32 input channels; no bias (added in conv_qkv)
    const int half = blockIdx.x / 192;
    const int sp = blockIdx.x - half*192;
    const int t = sp >> 5, y = sp & 31;
    const int x = tid & 31, cop = tid >> 5;   // 0..15
    float acc = 0.f;
    const int cbase = half*32;
    for (int ci0 = cbase; ci0 < cbase + 32; ci0 += 16) {
      __syncthreads();
      for (int e = tid; e < 4896; e += 512) {
        int ci = e / 306, rem = e - ci*306;
        int tz = rem / 102, rem2 = rem - tz*102;
        int dy = rem2 / 34, xx = rem2 - dy*34;
        int gt = t + tz - 1, gy = y + dy - 1, gx = xx - 1;
        float v = 0.f;
        if (gt >= 0 && gt < 6 && gy >= 0 && gy < 32 && gx >= 0 && gx < 32)
          v = in[((ci0 + ci)*6 + gt)*1024 + gy*32 + gx];
        win[e] = v;
      }
      __syncthreads();
      for (int ci = 0; ci < 16; ++ci) {
        const float* w0 = W + (cop*64 + ci0 + ci)*27;
        const float* wr = win + ci*306;
        #pragma unroll
        for (int tz = 0; tz < 3; ++tz)
          #pragma unroll
          for (int dy = 0; dy < 3; ++dy)
            #pragma unroll
            for (int dx = 0; dx < 3; ++dx)
              acc += wr[(tz*3 + dy)*34 + x + dx] * w0[(tz*3 + dy)*3 + dx];
      }
    }
    float* dst = half ? feat1 : feat0;
    dst[(t*1024 + y*32 + x)*16 + cop] = acc;
  } else if (blockIdx.x == 384) {
    const float t5f = times[0] * 5.0f;
    const double ct_d = rint((double)t5f);
    const int ct = (int)ct_d;
    const double rt = ((double)t5f - ct_d) * 2.0 / 5.0;
    const float rtf = (float)rt;
    if (tid == 0) {
      float iz = ((rtf + 1.0f)*5.0f - 1.0f) / 2.0f;
      float z0 = floorf(iz);
      meta[0] = iz - z0;
      meta[1] = z0;
      for (int d = 0; d < 5; ++d) {
        int ix = ct + d - 2; ix = ix < 0 ? 0 : (ix > 5 ? 5 : ix);
        meta[2 + d] = (float)ix;
      }
    }
    if (tid < 40) {
      int dt = tid >> 3, h = tid & 7;
      double tcd = rt - (double)(dt - 2) * 2.0 / 5.0;
      float rs = (float)tcd * 5.0f;
      float acc = bpb[h];
      for (int j = 0; j < 10; ++j) {
        float pr = rs * Bpe[j*3 + 0];
        acc += sinf(pr) * Wpb[j*8 + h] + cosf(pr) * Wpb[(30+j)*8 + h];
      }
      meta[16 + tid] = acc;
    }
    if (tid < 224) {
      int p = tid / 56, ky = (tid >> 3) % 7, h = tid & 7;
      float r = (float)(2*p - 3) * 0.25f - 2.0f * (float)(ky - 3);
      float accy = 0.f, accx = 0.f;
      for (int j = 0; j < 10; ++j) {
        float pry = r * Bpe[(10+j)*3 + 1];
        accy += sinf(pry) * Wpb[(10+j)*8 + h] + cosf(pry) * Wpb[(40+j)*8 + h];
        float prx = r * Bpe[(20+j)*3 + 2];
        accx += sinf(prx) * Wpb[(20+j)*8 + h] + cosf(prx) * Wpb[(50+j)*8 + h];
      }
      meta[64 + tid]  = accy;
      meta[288 + tid] = accx;
    }
  } else if (tid < 256) {
    const int rblk = blockIdx.x - 385;
    const int n = tid;
    unsigned short tmp[32];
    if (rblk < 126) {
      const int s = rblk;
      #pragma unroll
      for (int j = 0; j < 32; ++j) {
        int p = s*32 + j;
        float w = 0.f;
        if (p < 4000) {
          int dt = p / 800, r = p - dt*800;
          if (r < 784) w = W1[(dt*784 + r)*256 + n];
        } else {
          int j2 = p - 4000;
          if (j2 < 18) w = W1[(3920 + j2)*256 + n];
        }
        tmp[j] = f2bf(w);
      }
      unsigned short* dh = W1h + ((size_t)(s*256 + n))*32;
      #pragma unroll
      for (int v = 0; v < 4; ++v) {
        u16x8 xv;
        #pragma unroll
        for (int j = 0; j < 8; ++j) xv[j] = tmp[v*8 + j];
        *(u16x8*)(dh + v*8) = xv;
      }
    } else {
      const int blk = rblk - 126;
      const int m = blk >> 3, s = blk & 7;
      const float* Wm = (m == 0) ? W2 : ((m == 1) ? W3 : W4);
      #pragma unroll
      for (int j = 0; j < 32; ++j) tmp[j] = f2bf(Wm[(s*32 + j)*256 + n]);
      unsigned short* dh = W234h + (size_t)m*65536 + ((size_t)(s*256 + n))*32;
      #pragma unroll
      for (int v = 0; v < 4; ++v) {
        u16x8 xv;
        #pragma unroll
        for (int j = 0; j < 8; ++j) xv[j] = tmp[v*8 + j];
        *(u16x8*)(dh + v*8) = xv;
      }
    }
  }
}

// ---------------- fused conv q/k/v; grid 576 = 3 mats x 192 (t,y); combines feat partials ----------------
__global__ __launch_bounds__(512) void conv_qkv_kernel(
    const float* __restrict__ f0, const float* __restrict__ f1,
    const float* __restrict__ bch,
    const float* __restrict__ Wq, const float* __restrict__ bq,
    const float* __restrict__ Wk, const float* __restrict__ bk,
    const float* __restrict__ Wv, const float* __restrict__ bv,
    float* __restrict__ fq, float* __restrict__ fk, float* __restrict__ fv) {
  __shared__ float win[4896];
  __shared__ float sbch[16];
  const int blk = blockIdx.x;
  const int m = blk / 192;                  // block-uniform matrix select
  const int sp = blk - m*192;
  const int t = sp >> 5, y = sp & 31;
  const int tid = threadIdx.x;
  const int x = tid & 31, cop = tid >> 5;   // 0..15
  if (tid < 16) sbch[tid] = bch[tid];
  __syncthreads();
  for (int e = tid; e < 4896; e += 512) {
    int tz = e / 1632, rem = e - tz*1632;
    int dy = rem / 544, rem2 = rem - dy*544;
    int ci = rem2 / 34, xx = rem2 - ci*34;
    int gt = t + tz - 1, gy = y + dy - 1, gx = xx - 1;
    float v = 0.f;
    if (gt >= 0 && gt < 6 && gy >= 0 && gy < 32 && gx >= 0 && gx < 32) {
      const int idx = ((gt*32 + gy)*32 + gx)*16 + ci;
      v = f0[idx] + f1[idx] + sbch[ci];
    }
    win[e] = v;
  }
  __syncthreads();
  const float* Wm = (m == 0) ? Wq : ((m == 1) ? Wk : Wv);
  const float* bm = (m == 0) ? bq : ((m == 1) ? bk : bv);
  float*       fm = (m == 0) ? fq : ((m == 1) ? fk : fv);
  float a0 = 0.f, a1 = 0.f;                 // 2-way chain split (ci parity)
  for (int ci = 0; ci < 16; ci += 2) {
    const float* w0 = Wm + (cop*16 + ci)*27;
    #pragma unroll
    for (int tz = 0; tz < 3; ++tz)
      #pragma unroll
      for (int dy = 0; dy < 3; ++dy) {
        const float* wr0 = win + ((tz*3 + dy)*16 + ci)*34 + x;
        #pragma unroll
        for (int dx = 0; dx < 3; ++dx) {
          const int tap = (tz*3 + dy)*3 + dx;
          a0 += wr0[dx]      * w0[tap];
          a1 += wr0[34 + dx] * w0[27 + tap];
        }
      }
  }
  fm[(t*1024 + y*32 + x)*16 + cop] = a0 + a1 + bm[cop];
}

// ---------------- attn dt-phase body (compile-time chunk range) ----------------
template<int CHL, int CHH>
__device__ __forceinline__ void attn_dt(
    int dt, int cj0, int ci0, int tid,
    int q, int h, int ay, int ax, int py, int px,
    int goct, int qr, int nb0,
    const float* __restrict__ fk, const float* __restrict__ fv,
    const unsigned short* __restrict__ W1h,
    const float* sPt, const float* sPy, const float* sPx, const float* sMeta,
    const float* sQh, float* sK, float* sV,
    unsigned short* sA0, unsigned short* sA1,
    f32x4 (&acc)[4][2]) {
  __syncthreads();
  const int tg = (int)sMeta[2 + dt];
  for (int e = tid; e < 2048; e += 512) {
    const int sel = e >> 10, r = e & 1023;
    const int wy8 = r >> 7, wx8 = (r >> 4) & 7, c = r & 15;
    const int gy = cj0 + wy8 - 3, gx = ci0 + wx8 - 3;
    float v = 0.f;
    if (gy >= 0 && gy < 32 && gx >= 0 && gx < 32)
      v = (sel ? fv : fk)[((tg*32 + gy)*32 + gx)*16 + c];
    (sel ? sV : sK)[r] = v;
  }
  __syncthreads();

  // pass 1: exps into registers + denom (no max-subtraction; |score| small)
  const float qv0 = sQh[q*16 + 2*h], qv1 = sQh[q*16 + 2*h + 1];
  const float ptv = sPt[dt*8 + h];
  float ev[49];
  float ssum = 0.f;
  #pragma unroll
  for (int ky = 0; ky < 7; ++ky) {
    const float basey = ptv + sPy[(py*7 + ky)*8 + h];
    #pragma unroll
    for (int kx = 0; kx < 7; ++kx) {
      const float2 kv = *(const float2*)&sK[((ay + ky)*8 + ax + kx)*16 + 2*h];
      const float sc = (qv0*kv.x + qv1*kv.y) * 0.70710678118654752f + basey + sPx[(px*7 + kx)*8 + h];
      const float x = __expf(sc);
      ev[ky*7 + kx] = x;
      ssum += x;
    }
  }
  const float dinv = 1.f / ssum;

#define FILL_CHUNK(CH, BUF) do {                                            \
    _Pragma("unroll")                                                       \
    for (int kk = 0; kk < 10; ++kk) {                                       \
      const int k = (CH)*10 + kk;                                           \
      float a0 = 0.f, a1 = 0.f;                                             \
      if (k < 49) {                                                         \
        const int ky = k / 7, kx = k - ky*7;                                \
        const float e2 = ev[k] * dinv;                                      \
        const float2 vv = *(const float2*)&sV[((ay + ky)*8 + ax + kx)*16 + 2*h]; \
        a0 = e2 * vv.x; a1 = e2 * vv.y;                                     \
      }                                                                     \
      const int off = ((((kk >> 1)*4 + (kk & 1)*2 + (h >> 2))*4 + (q >> 4))*16 + (q & 15))*8 + 2*(h & 3); \
      *(unsigned int*)&(BUF)[off] = cvt_pk_bf16(a0, a1);                    \
    } } while (0)

  FILL_CHUNK(CHL, sA0);
  __syncthreads();
  #pragma unroll
  for (int ch = CHL; ch <= CHH; ++ch) {
    unsigned short* bufR = ((ch - CHL) & 1) ? sA1 : sA0;
    unsigned short* bufW = ((ch - CHL) & 1) ? sA0 : sA1;
    // GEMM on bufR (5 k-steps, 4 m-tiles x 2 n-tiles), overlapped with fill of ch+1
    #pragma unroll
    for (int sc2 = 0; sc2 < 5; ++sc2) {
      const int s_g = dt*25 + ch*5 + sc2;
      const unsigned short* bh_p = W1h + (size_t)(s_g*256 + nb0 + qr)*32 + goct*8;
      const bf16x8 bh0 = *(const bf16x8*)bh_p;
      const bf16x8 bh1 = *(const bf16x8*)(bh_p + 512);
      #pragma unroll
      for (int mt = 0; mt < 4; ++mt) {
        const int aoff = (((sc2*4 + goct)*4 + mt)*16 + qr)*8;
        const bf16x8 ah = *(const bf16x8*)&bufR[aoff];
        acc[mt][0] = __builtin_amdgcn_mfma_f32_16x16x32_bf16(ah, bh0, acc[mt][0], 0, 0, 0);
        acc[mt][1] = __builtin_amdgcn_mfma_f32_16x16x32_bf16(ah, bh1, acc[mt][1], 0, 0, 0);
      }
    }
    if (ch < CHH) FILL_CHUNK(ch + 1, bufW);
    __syncthreads();
  }
#undef FILL_CHUNK
}

// ---------------- fused attention + MLP layer 1 (MFMA, A=bf16, W1=bf16) ----------------
// grid 512: block = 2x2 cells (64 q) x K-half (dt-split). 512 threads = 8 waves.
__global__ __launch_bounds__(512, 4) void attn_l1_kernel(
    const float* __restrict__ fq, const float* __restrict__ fk,
    const float* __restrict__ fv, const float* __restrict__ meta,
    const unsigned short* __restrict__ W1h,
    float* __restrict__ hA0, float* __restrict__ hA1) {
  __shared__ float sPt[40], sPy[224], sPx[224], sMeta[8];
  __shared__ float sQh[1024];
  __shared__ float sK[1024], sV[1024];
  __shared__ __align__(16) unsigned short sA0[10240];  // [5 sl][4 g][4 mt][16 q][8]
  __shared__ __align__(16) unsigned short sA1[10240];

  const int tid = threadIdx.x;
  const int cp = blockIdx.x >> 1, bh = blockIdx.x & 1;
  const int cj0 = (cp >> 4) * 2, ci0 = (cp & 15) * 2;

  if (tid < 8) sMeta[tid] = meta[tid];
  if (tid < 40) sPt[tid] = meta[16 + tid];
  if (tid < 224) { sPy[tid] = meta[64 + tid]; sPx[tid] = meta[288 + tid]; }
  __syncthreads();
  const float wz = sMeta[0];
  const int z0 = (int)sMeta[1];
  const int tgz0 = (int)sMeta[2 + z0];
  const int tgz1 = (int)sMeta[3 + z0];

  // trilinear sample of feat_q -> sQh[q][c], q in 0..63 (8x8 pixel patch)
  for (int e = tid; e < 1024; e += 512) {
    const int q = e >> 4, c = e & 15;
    const int pyp = q >> 3, pxp = q & 7;
    const int cj = cj0 + (pyp >> 2), ci = ci0 + (pxp >> 2);
    const int py = pyp & 3, px = pxp & 3;
    const int y0 = cj + ((py < 2) ? -1 : 0);
    const int x0 = ci + ((px < 2) ? -1 : 0);
    const float wy = (py == 0) ? 0.625f : (py == 1) ? 0.875f : (py == 2) ? 0.125f : 0.375f;
    const float wx = (px == 0) ? 0.625f : (px == 1) ? 0.875f : (px == 2) ? 0.125f : 0.375f;
    float s = 0.f;
    #pragma unroll
    for (int dz = 0; dz < 2; ++dz) {
      const int tg = dz ? tgz1 : tgz0;
      const float wzz = dz ? wz : (1.f - wz);
      #pragma unroll
      for (int dy = 0; dy < 2; ++dy) {
        const int yy = y0 + dy;
        const float wyy = dy ? wy : (1.f - wy);
        if (yy < 0 || yy > 31) continue;
        #pragma unroll
        for (int dx = 0; dx < 2; ++dx) {
          const int xx = x0 + dx;
          const float wxx = dx ? wx : (1.f - wx);
          if (xx < 0 || xx > 31) continue;
          s += ((wzz * wyy) * wxx) * fq[((tg*32 + yy)*32 + xx)*16 + c];
        }
      }
    }
    sQh[e] = s;
  }

  f32x4 acc[4][2];
  #pragma unroll
  for (int a = 0; a < 4; ++a) {
    acc[a][0] = (f32x4){0.f, 0.f, 0.f, 0.f};
    acc[a][1] = (f32x4){0.f, 0.f, 0.f, 0.f};
  }

  const int lane = tid & 63, wid = tid >> 6;
  const int goct = lane >> 4, qr = lane & 15;
  const int nb0 = wid * 32;
  const int q = tid >> 3, h = tid & 7;
  const int ay = q >> 5, ax = (q >> 2) & 1;
  const int py = (q >> 3) & 3, px = q & 3;

  if (!bh) {
    attn_dt<0,4>(0, cj0, ci0, tid, q, h, ay, ax, py, px, goct, qr, nb0,
                 fk, fv, W1h, sPt, sPy, sPx, sMeta, sQh, sK, sV, sA0, sA1, acc);
    attn_dt<0,4>(1, cj0, ci0, tid, q, h, ay, ax, py, px, goct, qr, nb0,
                 fk, fv, W1h, sPt, sPy, sPx, sMeta, sQh, sK, sV, sA0, sA1, acc);
    attn_dt<0,1>(2, cj0, ci0, tid, q, h, ay, ax, py, px, goct, qr, nb0,
                 fk, fv, W1h, sPt, sPy, sPx, sMeta, sQh, sK, sV, sA0, sA1, acc);
    // tail k-step: 16 rows of sq + 2 rows of 0.5 + 14 zero rows
    __syncthreads();
    for (int e = tid; e < 2048; e += 512) {
      const int q2 = e >> 5, r2 = e & 31;
      const float a = (r2 < 16) ? sQh[q2*16 + r2] : ((r2 < 18) ? 0.5f : 0.f);
      const int off = ((((r2 >> 3))*4 + (q2 >> 4))*16 + (q2 & 15))*8 + (r2 & 7);
      sA0[off] = f2bf(a);
    }
    __syncthreads();
    const unsigned short* bh_p = W1h + (size_t)(125*256 + nb0 + qr)*32 + goct*8;
    const bf16x8 bh0 = *(const bf16x8*)bh_p;
    const bf16x8 bh1 = *(const bf16x8*)(bh_p + 512);
    #pragma unroll
    for (int mt = 0; mt < 4; ++mt) {
      const int aoff = ((goct*4 + mt)*16 + qr)*8;
      const bf16x8 ah = *(const bf16x8*)&sA0[aoff];
      acc[mt][0] = __builtin_amdgcn_mfma_f32_16x16x32_bf16(ah, bh0, acc[mt][0], 0, 0, 0);
      acc[mt][1] = __builtin_amdgcn_mfma_f32_16x16x32_bf16(ah, bh1, acc[mt][1], 0, 0, 0);
    }
  } else {
    attn_dt<2,4>(2, cj0, ci0, tid, q, h, ay, ax, py, px, goct, qr, nb0,
                 fk, fv, W1h, sPt, sPy, sPx, sMeta, sQh, sK, sV, sA0, sA1, acc);
    attn_dt<0,4>(3, cj0, ci0, tid, q, h, ay, ax, py, px, goct, qr, nb0,
                 fk, fv, W1h, sPt, sPy, sPx, sMeta, sQh, sK, sV, sA0, sA1, acc);
    attn_dt<0,4>(4, cj0, ci0, tid, q, h, ay, ax, py, px, goct, qr, nb0,
                 fk, fv, W1h, sPt, sPy, sPx, sMeta, sQh, sK, sV, sA0, sA1, acc);
  }

  // epilogue: raw partial store
  float* hp = bh ? hA1 : hA0;
  #pragma unroll
  for (int nt = 0; nt < 2; ++nt) {
    const int n = nb0 + nt*16 + qr;
    #pragma unroll
    for (int mt = 0; mt < 4; ++mt) {
      #pragma unroll
      for (int r = 0; r < 4; ++r) {
        const int ql = mt*16 + goct*4 + r;
        const int row = (cj0*4 + (ql >> 3))*128 + ci0*4 + (ql & 7);
        hp[row*NH + n] = acc[mt][nt][r];
      }
    }
  }
}

// ---------------- fused MLP l2+l3+l4+out: block = 32 rows, grid 512 ----------------
__global__ __launch_bounds__(512) void mlp234o_kernel(
    const float* __restrict__ hA0, const float* __restrict__ hA1,
    const unsigned short* __restrict__ W234h, const float* __restrict__ b1,
    const float* __restrict__ b2, const float* __restrict__ b3,
    const float* __restrict__ b4, const float* __restrict__ W5,
    const float* __restrict__ b5, float* __restrict__ out) {
  __shared__ __align__(16) unsigned short aH[8192];  // [s8][g4][mt2][q16][e8]
  __shared__ __align__(16) unsigned short aL[8192];
  __shared__ float sW5[768];
  __shared__ float sB5[3];

  const int tid = threadIdx.x, lane = tid & 63, wid = tid >> 6;
  const int goct = lane >> 4, qr = lane & 15, nb0 = wid * 32;
  const int qbase = blockIdx.x * 32;

  for (int e = tid; e < 768; e += 512) sW5[e] = W5[e];
  if (tid < 3) sB5[tid] = b5[tid];

  // combine partials -> h1 = gelu(p0+p1+b1) -> a-frag layout (hi/lo)
  {
    #pragma unroll
    for (int u = 0; u < 2; ++u) {
      const int idx = tid*2 + u;
      const int q0_ = idx >> 5, rem = idx & 31;
      const int s0_ = rem >> 2, g = rem & 3;
      const size_t off = (size_t)(qbase + q0_)*NH + s0_*32 + g*8;
      const float4 pa0 = *(const float4*)(hA0 + off);
      const float4 pa1 = *(const float4*)(hA0 + off + 4);
      const float4 pb0 = *(const float4*)(hA1 + off);
      const float4 pb1 = *(const float4*)(hA1 + off + 4);
      const float4 bb0 = *(const float4*)(b1 + s0_*32 + g*8);
      const float4 bb1 = *(const float4*)(b1 + s0_*32 + g*8 + 4);
      float vals[8] = {pa0.x + pb0.x + bb0.x, pa0.y + pb0.y + bb0.y,
                       pa0.z + pb0.z + bb0.z, pa0.w + pb0.w + bb0.w,
                       pa1.x + pb1.x + bb1.x, pa1.y + pb1.y + bb1.y,
                       pa1.z + pb1.z + bb1.z, pa1.w + pb1.w + bb1.w};
      bf16x8 hiv, lov;
      #pragma unroll
      for (int j = 0; j < 8; ++j) {
        const float v = gelu_f(vals[j]);
        unsigned short h_, l_;
        split2(v, h_, l_);
        hiv[j] = (short)h_; lov[j] = (short)l_;
      }
      const int ao = (((s0_*4 + g)*2 + (q0_ >> 4))*16 + (q0_ & 15))*8;
      *(bf16x8*)&aH[ao] = hiv;
      *(bf16x8*)&aL[ao] = lov;
    }
  }

  for (int layer = 0; layer < 3; ++layer) {
    const unsigned short* Wh = W234h + (size_t)layer*65536;
    const float* bptr = (layer == 0) ? b2 : ((layer == 1) ? b3 : b4);
    __syncthreads();
    f32x4 acc[2][2];
    #pragma unroll
    for (int a = 0; a < 2; ++a) {
      acc[a][0] = (f32x4){0.f, 0.f, 0.f, 0.f};
      acc[a][1] = (f32x4){0.f, 0.f, 0.f, 0.f};
    }
    #pragma unroll
    for (int s = 0; s < 8; ++s) {
      const unsigned short* bh_p = Wh + (size_t)(s*256 + nb0 + qr)*32 + goct*8;
      const bf16x8 bh0 = *(const bf16x8*)bh_p;
      const bf16x8 bh1 = *(const bf16x8*)(bh_p + 512);
      #pragma unroll
      for (int mt = 0; mt < 2; ++mt) {
        const int aoff = (((s*4 + goct)*2 + mt)*16 + qr)*8;
        const bf16x8 ah = *(const bf16x8*)&aH[aoff];
        const bf16x8 al = *(const bf16x8*)&aL[aoff];
        acc[mt][0] = __builtin_amdgcn_mfma_f32_16x16x32_bf16(ah, bh0, acc[mt][0], 0, 0, 0);
        acc[mt][0] = __builtin_amdgcn_mfma_f32_16x16x32_bf16(al, bh0, acc[mt][0], 0, 0, 0);
        acc[mt][1] = __builtin_amdgcn_mfma_f32_16x16x32_bf16(ah, bh1, acc[mt][1], 0, 0, 0);
        acc[mt][1] = __builtin_amdgcn_mfma_f32_16x16x32_bf16(al, bh1, acc[mt][1], 0, 0, 0);
      }
    }
    __syncthreads();
    #pragma unroll
    for (int nt = 0; nt < 2; ++nt) {
      const int n = nb0 + nt*16 + qr;
      const float bb = bptr[n];
      #pragma unroll
      for (int mt = 0; mt < 2; ++mt) {
        #pragma unroll
        for (int r = 0; r < 4; ++r) {
          const int qq = mt*16 + goct*4 + r;
          const float v = gelu_f(acc[mt][nt][r] + bb);
          unsigned short h_, l_; split2(v, h_, l_);
          const int ao = ((((n >> 5)*4 + ((n >> 3) & 3))*2 + mt)*16 + (qq & 15))*8 + (n & 7);
          aH[ao] = h_; aL[ao] = l_;
        }
      }
    }
  }
  __syncthreads();
  if (tid < 96) {
    const int c = tid >> 5, qq = tid & 31;
    const int mt = qq >> 4, qrr = qq & 15;
    float a = sB5[c];
    #pragma unroll 4
    for (int k8 = 0; k8 < 32; ++k8) {
      const int ao = ((k8*2 + mt)*16 + qrr)*8;
      const bf16x8 hv = *(const bf16x8*)&aH[ao];
      const bf16x8 lv = *(const bf16x8*)&aL[ao];
      #pragma unroll
      for (int j = 0; j < 8; ++j)
        a += (bf2f((unsigned short)hv[j]) + bf2f((unsigned short)lv[j])) * sW5[(k8*8 + j)*3 + c];
    }
    out[c*16384 + qbase + qq] = a;
  }
}

// ---------------- launch ----------------
extern "C" void kernel_launch(void* const* d_in, const int* in_sizes, int n_in,
                              void* d_out, int out_size, void* d_ws, size_t ws_size,
                              hipStream_t stream) {
  const float* feat_img = (const float*)d_in[0];
  const float* times    = (const float*)d_in[2];
  const float* W_ch     = (const float*)d_in[3];
  const float* b_ch     = (const float*)d_in[4];
  const float* W_q      = (const float*)d_in[5];
  const float* b_q      = (const float*)d_in[6];
  const float* W_k      = (const float*)d_in[7];
  const float* b_k      = (const float*)d_in[8];
  const float* W_v      = (const float*)d_in[9];
  const float* b_v      = (const float*)d_in[10];
  const float* B_pe     = (const float*)d_in[11];
  const float* W_pb     = (const float*)d_in[12];
  const float* b_pb     = (const float*)d_in[13];
  const float* W1       = (const float*)d_in[14];
  const float* b1       = (const float*)d_in[15];
  const float* W2       = (const float*)d_in[16];
  const float* b2       = (const float*)d_in[17];
  const float* W3       = (const float*)d_in[18];
  const float* b3       = (const float*)d_in[19];
  const float* W4       = (const float*)d_in[20];
  const float* b4       = (const float*)d_in[21];
  const float* W5       = (const float*)d_in[22];
  const float* b5       = (const float*)d_in[23];

  char* wsb = (char*)d_ws;
  float* feat0 = (float*)(wsb + WSB_FEAT);
  float* feat1 = (float*)(wsb + WSB_FEAT1);
  float* fq   = (float*)(wsb + WSB_FQ);
  float* fk   = (float*)(wsb + WSB_FK);
  float* fv   = (float*)(wsb + WSB_FV);
  float* meta = (float*)(wsb + WSB_META);
  float* hA0  = (float*)(wsb + WSB_HA0);
  float* hA1  = (float*)(wsb + WSB_HA1);
  unsigned short* W1h   = (unsigned short*)(wsb + WSB_W1H);
  unsigned short* W234h = (unsigned short*)(wsb + WSB_W234);

  pre_kernel<<<535, 512, 0, stream>>>(feat_img, W_ch, times, B_pe, W_pb, b_pb,
                                      W1, W2, W3, W4, feat0, feat1, meta, W1h, W234h);
  conv_qkv_kernel<<<576, 512, 0, stream>>>(feat0, feat1, b_ch,
                                           W_q, b_q, W_k, b_k, W_v, b_v, fq, fk, fv);
  attn_l1_kernel<<<512, 512, 0, stream>>>(fq, fk, fv, meta, W1h, hA0, hA1);
  mlp234o_kernel<<<512, 512, 0, stream>>>(hA0, hA1, W234h, b1, b2, b3, b4, W5, b5, (float*)d_out);
}